// Round 11
// baseline (311.441 us; speedup 1.0000x reference)
//
#include <hip/hip_runtime.h>
#include <hip/hip_bf16.h>

// Problem constants (B=4, S=2048, D=1024, E=8, F=4096)
#define TOKENS   8192
#define DDIM     1024
#define NEXP     8
#define FDIM     4096
#define CAPACITY 1280
#define NYT      10         // CAPACITY / 128 M-tiles

typedef __attribute__((ext_vector_type(8))) __bf16 bf16x8;
typedef __attribute__((ext_vector_type(4))) __bf16 bf16x4;
typedef __attribute__((ext_vector_type(4))) float  f32x4;

typedef __attribute__((address_space(1))) const void gvoid_t;
typedef __attribute__((address_space(3))) void       lvoid_t;

__device__ __forceinline__ void async16(const void* g, void* l) {
  // 16B per lane; LDS dest = wave-uniform base + lane*16 (HW behavior)
  __builtin_amdgcn_global_load_lds((gvoid_t*)g, (lvoid_t*)l, 16, 0, 0);
}

// ---------------- gating: logits, softmax, top-1 (all f32, must match ref routing) --------
__global__ void gate_kernel(const float* __restrict__ x, const float* __restrict__ gw,
                            int* __restrict__ eidx, float* __restrict__ prob) {
  const int t = blockIdx.x;
  const int lane = threadIdx.x;           // 64 threads
  const float* xp = x + (size_t)t * DDIM;
  float acc[NEXP];
#pragma unroll
  for (int e = 0; e < NEXP; ++e) acc[e] = 0.f;
#pragma unroll 4
  for (int i = 0; i < DDIM / 64; ++i) {
    const int d = i * 64 + lane;
    const float xv = xp[d];
    const f32x4 g0 = *(const f32x4*)(gw + d * NEXP);
    const f32x4 g1 = *(const f32x4*)(gw + d * NEXP + 4);
    acc[0] += xv * g0[0]; acc[1] += xv * g0[1];
    acc[2] += xv * g0[2]; acc[3] += xv * g0[3];
    acc[4] += xv * g1[0]; acc[5] += xv * g1[1];
    acc[6] += xv * g1[2]; acc[7] += xv * g1[3];
  }
#pragma unroll
  for (int e = 0; e < NEXP; ++e) {
    float v = acc[e];
#pragma unroll
    for (int off = 32; off; off >>= 1) v += __shfl_xor(v, off);
    acc[e] = v;
  }
  if (lane == 0) {
    float m = acc[0]; int mi = 0;
#pragma unroll
    for (int e = 1; e < NEXP; ++e) if (acc[e] > m) { m = acc[e]; mi = e; }  // first-occurrence argmax
    float s = 0.f;
#pragma unroll
    for (int e = 0; e < NEXP; ++e) s += __expf(acc[e] - m);
    eidx[t] = mi;
    prob[t] = 1.f / s;       // softmax prob of the argmax expert
  }
}

// ---------------- deterministic per-expert cumsum positions + slot->token map + counts ----
__global__ void scan_kernel(const int* __restrict__ eidx, int* __restrict__ src,
                            int* __restrict__ counts) {
  __shared__ int buf[2][NEXP][256];
  const int tid = threadIdx.x;            // 256 threads, 1 block
  for (int i = tid; i < NEXP * CAPACITY; i += 256) src[i] = -1;
  const int t0 = tid * (TOKENS / 256);    // 32 tokens per thread
#pragma unroll
  for (int e = 0; e < NEXP; ++e) buf[0][e][tid] = 0;
  for (int k = 0; k < TOKENS / 256; ++k) {
    const int e = eidx[t0 + k];
    buf[0][e][tid]++;                     // LDS histogram
  }
  __syncthreads();
  int cur = 0;
  for (int off = 1; off < 256; off <<= 1) {   // Hillis-Steele inclusive scan over threads
#pragma unroll
    for (int e = 0; e < NEXP; ++e) {
      int v = buf[cur][e][tid];
      if (tid >= off) v += buf[cur][e][tid - off];
      buf[cur ^ 1][e][tid] = v;
    }
    __syncthreads();
    cur ^= 1;
  }
  if (tid < NEXP) counts[tid] = buf[cur][tid][255];   // per-expert totals (for M-tile skip)
  // exclusive base -> running counters in the other buffer (own slot only, no race)
#pragma unroll
  for (int e = 0; e < NEXP; ++e)
    buf[cur ^ 1][e][tid] = (tid > 0) ? buf[cur][e][tid - 1] : 0;
  for (int k = 0; k < TOKENS / 256; ++k) {
    const int t = t0 + k;
    const int e = eidx[t];
    const int p = buf[cur ^ 1][e][tid]++;
    if (p < CAPACITY) src[e * CAPACITY + p] = t;   // p>=CAP => token dropped
  }
}

// ---------------- dispatch: scatter tokens (f32 -> bf16) into [E*CAP, D]; zero empty slots
__global__ void dispatch_kernel(const float* __restrict__ tokens, const int* __restrict__ src,
                                __bf16* __restrict__ Xb) {
  const int slot = blockIdx.x;            // E*CAP blocks
  const int tid  = threadIdx.x;           // 256 threads, 4 elems each
  const int t = src[slot];
  bf16x4* dst = (bf16x4*)(Xb + (size_t)slot * DDIM);
  bf16x4 o;
  if (t >= 0) {
    const f32x4 v = ((const f32x4*)(tokens + (size_t)t * DDIM))[tid];
    o[0] = (__bf16)v[0]; o[1] = (__bf16)v[1]; o[2] = (__bf16)v[2]; o[3] = (__bf16)v[3];
  } else {
    o[0] = (__bf16)0.f; o[1] = (__bf16)0.f; o[2] = (__bf16)0.f; o[3] = (__bf16)0.f;
  }
  dst[tid] = o;
}

// ---------------- weight convert f32->bf16 with transpose: w[e][R][C] -> wt[e][C][R] ------
// Vectorized both sides (G13): f32x4 global reads, bf16x8 global writes; 64x64 LDS tile.
__global__ void transpose_convert_kernel(const float* __restrict__ w, __bf16* __restrict__ wt,
                                         int R, int C) {
  __shared__ __bf16 tile[64][66];         // pad 2: 8-row stride = 264 dwords % 32 != 0
  const int e = blockIdx.z;
  const float* wp = w + (size_t)e * R * C;
  __bf16* op = wt + (size_t)e * R * C;
  const int c0 = blockIdx.x * 64, r0 = blockIdx.y * 64;
  const int tid = threadIdx.x;            // 256 threads
#pragma unroll
  for (int p = 0; p < 4; ++p) {           // load 16 rows/pass, f32x4 per thread
    const int r = p * 16 + (tid >> 4);
    const int c = (tid & 15) * 4;
    const f32x4 v = *(const f32x4*)(wp + (size_t)(r0 + r) * C + c0 + c);
    tile[r][c]     = (__bf16)v[0]; tile[r][c + 1] = (__bf16)v[1];
    tile[r][c + 2] = (__bf16)v[2]; tile[r][c + 3] = (__bf16)v[3];
  }
  __syncthreads();
#pragma unroll
  for (int p = 0; p < 2; ++p) {           // store 32 out-rows/pass, bf16x8 per thread
    const int c  = p * 32 + (tid >> 3);   // output row (original column)
    const int rg = (tid & 7) * 8;         // 8 consecutive original rows
    bf16x8 o;
#pragma unroll
    for (int i = 0; i < 8; ++i) o[i] = tile[rg + i][c];
    *(bf16x8*)(op + (size_t)(c0 + c) * R + r0 + rg) = o;
  }
}

// ---------------- GEMM1: 128x128, BK=32, 4 waves, counted-vmcnt dbuf IN 32KB --------------
// H[e] = relu(Xb[e][M,K] @ W1T[e][N,K]^T) -> bf16.
// The untested combination: counted pipeline AND 2 blocks/CU simultaneously.
// Rounds 5/9/10 showed 64KB LDS -> 1 block/CU (occ ~12%) so dbuf always traded away
// the inter-block overlap that hid the stalls; BK=32 halves the tile so the double
// buffer fits in 32KB (occ ~17-21%, 2 blocks/CU). Skeleton = R10's proven counted
// schedule: phase(c) -> B1 -> stage(c,t+2) -> vmcnt(4) (tile t+1 landed, t+2 in
// flight) -> B2. Swizzle re-derived for 4-granule rows: g ^= (r&3)^((r>>2)&3)
// (bijective per row; rows {0,4,8,12} hit distinct bank quads).
__global__ __launch_bounds__(256, 2)
void gemm1_kernel(const __bf16* __restrict__ A, const __bf16* __restrict__ B,
                  __bf16* __restrict__ Cbf, const int* __restrict__ counts,
                  int K, size_t sA, size_t sB, size_t sC) {
  constexpr int N  = FDIM;
  constexpr int NX = N / 128;
  __shared__ __bf16 lds[2][2][128 * 32];  // [buf][A|B][128 rows][32 k] = 32 KB total

  const int nwg = NX * NYT * NEXP;
  int wg = blockIdx.x;
  wg = (wg & 7) * (nwg >> 3) + (wg >> 3); // bijective XCD swizzle (nwg % 8 == 0)
  const int e   = wg / (NX * NYT);
  const int rem = wg - e * (NX * NYT);
  const int ty  = rem % NYT;              // y fastest: consecutive ids share B-panel (L2)
  const int tx  = rem / NYT;
  const int m0  = ty * 128, n0 = tx * 128;

  const int cnt   = counts[e];            // M-tile skip
  const int tiles = (cnt + 127) >> 7;
  if (ty >= ((tiles < NYT) ? tiles : NYT)) return;

  const __bf16* Ae = A + (size_t)e * sA;
  const __bf16* Be = B + (size_t)e * sB;
  const int tid = threadIdx.x;
  const int wid = tid >> 6, lane = tid & 63;
  const int wm = wid >> 1, wn = wid & 1;  // 2x2 wave grid, per-wave out 64x64
  const int rl = lane & 15, gl = lane >> 4;

  f32x4 acc[4][4];
#pragma unroll
  for (int m = 0; m < 4; ++m)
#pragma unroll
    for (int n = 0; n < 4; ++n) acc[m][n] = (f32x4){0.f, 0.f, 0.f, 0.f};

  // 4 async16 per thread per stage (2 A + 2 B) -> vmcnt 4 per wave per stage
  auto stage = [&](int c, int kt) {
    const int k0 = kt * 32;
#pragma unroll
    for (int i = 0; i < 2; ++i) {
      const int chunk = i * 4 + wid;      // 0..7, uniform per wave
      const int s = chunk * 64 + lane;    // 16B slot id 0..511
      const int row = s >> 2;             // 4 granules per 32-k row
      const int cg  = (s & 3) ^ (row & 3) ^ ((row >> 2) & 3);   // pre-swizzled source
      async16(Ae + (size_t)(m0 + row) * K + k0 + cg * 8, &lds[c][0][chunk * 512]);
      async16(Be + (size_t)(n0 + row) * K + k0 + cg * 8, &lds[c][1][chunk * 512]);
    }
  };

  auto phase = [&](int c) {               // 8 ds_read_b128 -> 16 MFMA (one K=32 step)
    const char* la = (const char*)&lds[c][0][0];
    const char* lb = (const char*)&lds[c][1][0];
    bf16x8 af[4], bv[4];
#pragma unroll
    for (int m = 0; m < 4; ++m) {
      const int rowin = wm * 64 + m * 16 + rl;
      const int g = gl ^ (rowin & 3) ^ ((rowin >> 2) & 3);
      af[m] = *(const bf16x8*)(la + rowin * 64 + g * 16);
    }
#pragma unroll
    for (int n = 0; n < 4; ++n) {
      const int rowin = wn * 64 + n * 16 + rl;
      const int g = gl ^ (rowin & 3) ^ ((rowin >> 2) & 3);
      bv[n] = *(const bf16x8*)(lb + rowin * 64 + g * 16);
    }
#pragma unroll
    for (int m = 0; m < 4; ++m)
#pragma unroll
      for (int n = 0; n < 4; ++n)
        acc[m][n] = __builtin_amdgcn_mfma_f32_16x16x32_bf16(af[m], bv[n], acc[m][n], 0, 0, 0);
  };

  const int nkt = K >> 5;                 // 32
  stage(0, 0);
  stage(1, 1);
  asm volatile("s_waitcnt vmcnt(4)" ::: "memory");   // tile 0 landed; tile 1 in flight
  __builtin_amdgcn_sched_barrier(0);
  __builtin_amdgcn_s_barrier();
  __builtin_amdgcn_sched_barrier(0);

  for (int t = 0; t < nkt; ++t) {
    const int c = t & 1;
    phase(c);
    if (t + 1 < nkt) {
      __builtin_amdgcn_sched_barrier(0);
      __builtin_amdgcn_s_barrier();       // B1: all waves done reading buf c
      __builtin_amdgcn_sched_barrier(0);
      if (t + 2 < nkt) {
        stage(c, t + 2);                  // overwrite dead buf c with tile t+2
        asm volatile("s_waitcnt vmcnt(4)" ::: "memory");  // tile t+1 retired (t+2 in flight)
      } else {
        asm volatile("s_waitcnt vmcnt(0)" ::: "memory");  // epilogue drain (last 2 tiles)
      }
      __builtin_amdgcn_sched_barrier(0);
      __builtin_amdgcn_s_barrier();       // B2: buf c^1 (tile t+1) visible to all
      __builtin_amdgcn_sched_barrier(0);
    }
  }

  // C/D layout: col = lane&15, row = (lane>>4)*4 + reg  [m89/m91 verified]
  __bf16* Ce = Cbf + (size_t)e * sC;
#pragma unroll
  for (int m = 0; m < 4; ++m)
#pragma unroll
    for (int j = 0; j < 4; ++j) {
      const int row = m0 + wm * 64 + m * 16 + gl * 4 + j;
#pragma unroll
      for (int n = 0; n < 4; ++n) {
        const int col = n0 + wn * 64 + n * 16 + rl;
        float v = acc[m][n][j];
        v = v > 0.f ? v : 0.f;            // fused ReLU
        Ce[(size_t)row * N + col] = (__bf16)v;
      }
    }
}

// ---------------- GEMM2: 128x128, BK=64, 4 waves, fused f32-W transpose (R8, 146us) -------
// out[t] = prob[t] * (H[e] @ W2[e][K][N])[slot].  W2 f32 consumed directly; B-tile
// reg-staged (8x f32x4 coalesced) -> cvt -> transposed swizzled ds_write_b128.
// Frozen at the measured-best R8 form while gemm1 tests the BK=32 pipeline.
__global__ __launch_bounds__(256, 2)
void gemm2_kernel(const __bf16* __restrict__ A, const float* __restrict__ Bw,
                  float* __restrict__ out, const int* __restrict__ src,
                  const float* __restrict__ prob, const int* __restrict__ counts,
                  int K, size_t sA, size_t sBw) {
  constexpr int N  = DDIM;
  constexpr int NX = N / 128;
  __shared__ __bf16 lds[2][128 * 64];     // [0]=A tile [128 m][64 k], [1]=B tile [128 n][64 k]

  const int nwg = NX * NYT * NEXP;
  int wg = blockIdx.x;
  wg = (wg & 7) * (nwg >> 3) + (wg >> 3); // bijective XCD swizzle (nwg % 8 == 0)
  const int e   = wg / (NX * NYT);
  const int rem = wg - e * (NX * NYT);
  const int ty  = rem % NYT;
  const int tx  = rem / NYT;
  const int m0  = ty * 128, n0 = tx * 128;

  const int cnt   = counts[e];            // M-tile skip
  const int tiles = (cnt + 127) >> 7;
  if (ty >= ((tiles < NYT) ? tiles : NYT)) return;

  const __bf16* Ae = A + (size_t)e * sA;
  const float*  Be = Bw + (size_t)e * sBw;     // [K][N] f32
  const int tid = threadIdx.x;
  const int wid = tid >> 6, lane = tid & 63;
  const int wm = wid >> 1, wn = wid & 1;
  const int rl = lane & 15, gl = lane >> 4;
  const int nq = tid & 31;                // B staging: n-quad (cols 4nq..4nq+3)
  const int kb = tid >> 5;                // B staging: k-granule (rows 8kb..8kb+7)

  f32x4 acc[4][4];
#pragma unroll
  for (int m = 0; m < 4; ++m)
#pragma unroll
    for (int n = 0; n < 4; ++n) acc[m][n] = (f32x4){0.f, 0.f, 0.f, 0.f};

  for (int kt = 0; kt < K; kt += 64) {
    // B: coalesced f32 reads (rows k, consecutive n)
    f32x4 r[8];
#pragma unroll
    for (int i = 0; i < 8; ++i)
      r[i] = *(const f32x4*)(Be + (size_t)(kt + kb * 8 + i) * N + n0 + nq * 4);
    // A: async16, source pre-swizzled (m173 pattern)
#pragma unroll
    for (int i = 0; i < 4; ++i) {
      const int s   = (wid * 4 + i) * 64 + lane;
      const int row = s >> 3;
      const int cg  = (s & 7) ^ (row & 7);
      async16(Ae + (size_t)(m0 + row) * K + kt + cg * 8, &lds[0][(wid * 4 + i) * 512]);
    }
    // B: convert + transposed swizzled ds_write_b128
#pragma unroll
    for (int i2 = 0; i2 < 4; ++i2) {
      const int n  = nq * 4 + i2;
      const int sl = kb ^ (n & 7) ^ ((n >> 3) & 7);
      bf16x8 o;
#pragma unroll
      for (int i = 0; i < 8; ++i) o[i] = (__bf16)r[i][i2];
      *(bf16x8*)((char*)&lds[1][0] + n * 128 + sl * 16) = o;
    }
    __syncthreads();                      // drains vmcnt (async16) + lgkmcnt (ds_write)
    const char* la = (const char*)&lds[0][0];
    const char* lb = (const char*)&lds[1][0];
#pragma unroll
    for (int kk = 0; kk < 2; ++kk) {
      bf16x8 af[4], bv[4];
#pragma unroll
      for (int m = 0; m < 4; ++m) {
        const int rowin = wm * 64 + m * 16 + rl;
        af[m] = *(const bf16x8*)(la + rowin * 128 + (((kk * 4 + gl) ^ (rowin & 7)) * 16));
      }
#pragma unroll
      for (int n = 0; n < 4; ++n) {
        const int rowin = wn * 64 + n * 16 + rl;
        const int sl = (kk * 4 + gl) ^ (rowin & 7) ^ ((rowin >> 3) & 7);
        bv[n] = *(const bf16x8*)(lb + rowin * 128 + sl * 16);
      }
#pragma unroll
      for (int m = 0; m < 4; ++m)
#pragma unroll
        for (int n = 0; n < 4; ++n)
          acc[m][n] = __builtin_amdgcn_mfma_f32_16x16x32_bf16(af[m], bv[n], acc[m][n], 0, 0, 0);
    }
    __syncthreads();
  }

  // epilogue: fused combine (scale + scatter)
#pragma unroll
  for (int m = 0; m < 4; ++m)
#pragma unroll
    for (int j = 0; j < 4; ++j) {
      const int slot = m0 + wm * 64 + m * 16 + gl * 4 + j;
      const int t = src[e * CAPACITY + slot];
      if (t >= 0) {
        const float p = prob[t];
        float* op = out + (size_t)t * N;
#pragma unroll
        for (int n = 0; n < 4; ++n) {
          const int col = n0 + wn * 64 + n * 16 + rl;
          op[col] = p * acc[m][n][j];
        }
      }
    }
}

extern "C" void kernel_launch(void* const* d_in, const int* in_sizes, int n_in,
                              void* d_out, int out_size, void* d_ws, size_t ws_size,
                              hipStream_t stream) {
  const float* x  = (const float*)d_in[0];
  const float* gw = (const float*)d_in[1];
  const float* w1 = (const float*)d_in[2];
  const float* w2 = (const float*)d_in[3];
  float* out = (float*)d_out;

  char* ws = (char*)d_ws;
  size_t off = 0;
  auto alloc = [&](size_t bytes) {
    void* p = ws + off;
    off += (bytes + 255) & ~(size_t)255;
    return p;
  };
  __bf16* W1bT = (__bf16*)alloc((size_t)NEXP * FDIM * DDIM * 2);   // [E][F][D] bf16
  __bf16* Xb   = (__bf16*)alloc((size_t)NEXP * CAPACITY * DDIM * 2);
  __bf16* Hb   = (__bf16*)alloc((size_t)NEXP * CAPACITY * FDIM * 2);
  int*   eidx  = (int*)alloc(TOKENS * sizeof(int));
  float* prob  = (float*)alloc(TOKENS * sizeof(float));
  int*   srcm  = (int*)alloc(NEXP * CAPACITY * sizeof(int));
  int*   cnts  = (int*)alloc(NEXP * sizeof(int));
  (void)ws_size; (void)in_sizes; (void)n_in;

  hipMemsetAsync(d_out, 0, (size_t)out_size * sizeof(float), stream);  // dropped tokens -> 0

  gate_kernel<<<TOKENS, 64, 0, stream>>>(x, gw, eidx, prob);
  scan_kernel<<<1, 256, 0, stream>>>(eidx, srcm, cnts);
  dispatch_kernel<<<NEXP * CAPACITY, 256, 0, stream>>>(x, srcm, Xb);
  transpose_convert_kernel<<<dim3(FDIM / 64, DDIM / 64, NEXP), 256, 0, stream>>>(
      w1, W1bT, DDIM, FDIM);
  // H = relu(Xb @ W1^T): bf16 B, BK=32 counted-dbuf in 32KB, grid = 32*10*8 = 2560
  gemm1_kernel<<<(FDIM / 128) * NYT * NEXP, 256, 0, stream>>>(
      Xb, W1bT, Hb, cnts,
      DDIM, (size_t)CAPACITY * DDIM, (size_t)FDIM * DDIM, (size_t)CAPACITY * FDIM);
  // out[t] = prob[t] * (H @ W2)[slot]: f32 W2 direct, BK=64, grid = 8*10*8 = 640
  gemm2_kernel<<<(DDIM / 128) * NYT * NEXP, 256, 0, stream>>>(
      Hb, w2, out, srcm, prob, cnts,
      FDIM, (size_t)CAPACITY * FDIM, (size_t)FDIM * DDIM);
}

// Round 12
// 309.525 us; speedup vs baseline: 1.0062x; 1.0062x over previous
//
#include <hip/hip_runtime.h>
#include <hip/hip_bf16.h>

// Problem constants (B=4, S=2048, D=1024, E=8, F=4096)
#define TOKENS   8192
#define DDIM     1024
#define NEXP     8
#define FDIM     4096
#define CAPACITY 1280
#define NYT      10         // CAPACITY / 128 M-tiles (gemm2)
#define NYT1     5          // CAPACITY / 256 M-tiles (gemm1)

typedef __attribute__((ext_vector_type(8))) __bf16 bf16x8;
typedef __attribute__((ext_vector_type(4))) __bf16 bf16x4;
typedef __attribute__((ext_vector_type(4))) float  f32x4;

typedef __attribute__((address_space(1))) const void gvoid_t;
typedef __attribute__((address_space(3))) void       lvoid_t;

__device__ __forceinline__ void async16(const void* g, void* l) {
  // 16B per lane; LDS dest = wave-uniform base + lane*16 (HW behavior)
  __builtin_amdgcn_global_load_lds((gvoid_t*)g, (lvoid_t*)l, 16, 0, 0);
}

#define SBAR do { __builtin_amdgcn_sched_barrier(0); __builtin_amdgcn_s_barrier(); \
                  __builtin_amdgcn_sched_barrier(0); } while (0)

// ---------------- gating: logits, softmax, top-1 (all f32, must match ref routing) --------
__global__ void gate_kernel(const float* __restrict__ x, const float* __restrict__ gw,
                            int* __restrict__ eidx, float* __restrict__ prob) {
  const int t = blockIdx.x;
  const int lane = threadIdx.x;           // 64 threads
  const float* xp = x + (size_t)t * DDIM;
  float acc[NEXP];
#pragma unroll
  for (int e = 0; e < NEXP; ++e) acc[e] = 0.f;
#pragma unroll 4
  for (int i = 0; i < DDIM / 64; ++i) {
    const int d = i * 64 + lane;
    const float xv = xp[d];
    const f32x4 g0 = *(const f32x4*)(gw + d * NEXP);
    const f32x4 g1 = *(const f32x4*)(gw + d * NEXP + 4);
    acc[0] += xv * g0[0]; acc[1] += xv * g0[1];
    acc[2] += xv * g0[2]; acc[3] += xv * g0[3];
    acc[4] += xv * g1[0]; acc[5] += xv * g1[1];
    acc[6] += xv * g1[2]; acc[7] += xv * g1[3];
  }
#pragma unroll
  for (int e = 0; e < NEXP; ++e) {
    float v = acc[e];
#pragma unroll
    for (int off = 32; off; off >>= 1) v += __shfl_xor(v, off);
    acc[e] = v;
  }
  if (lane == 0) {
    float m = acc[0]; int mi = 0;
#pragma unroll
    for (int e = 1; e < NEXP; ++e) if (acc[e] > m) { m = acc[e]; mi = e; }  // first-occurrence argmax
    float s = 0.f;
#pragma unroll
    for (int e = 0; e < NEXP; ++e) s += __expf(acc[e] - m);
    eidx[t] = mi;
    prob[t] = 1.f / s;       // softmax prob of the argmax expert
  }
}

// ---------------- deterministic per-expert cumsum positions + slot->token map + counts ----
__global__ void scan_kernel(const int* __restrict__ eidx, int* __restrict__ src,
                            int* __restrict__ counts) {
  __shared__ int buf[2][NEXP][256];
  const int tid = threadIdx.x;            // 256 threads, 1 block
  for (int i = tid; i < NEXP * CAPACITY; i += 256) src[i] = -1;
  const int t0 = tid * (TOKENS / 256);    // 32 tokens per thread
#pragma unroll
  for (int e = 0; e < NEXP; ++e) buf[0][e][tid] = 0;
  for (int k = 0; k < TOKENS / 256; ++k) {
    const int e = eidx[t0 + k];
    buf[0][e][tid]++;                     // LDS histogram
  }
  __syncthreads();
  int cur = 0;
  for (int off = 1; off < 256; off <<= 1) {   // Hillis-Steele inclusive scan over threads
#pragma unroll
    for (int e = 0; e < NEXP; ++e) {
      int v = buf[cur][e][tid];
      if (tid >= off) v += buf[cur][e][tid - off];
      buf[cur ^ 1][e][tid] = v;
    }
    __syncthreads();
    cur ^= 1;
  }
  if (tid < NEXP) counts[tid] = buf[cur][tid][255];   // per-expert totals (for M-tile skip)
  // exclusive base -> running counters in the other buffer (own slot only, no race)
#pragma unroll
  for (int e = 0; e < NEXP; ++e)
    buf[cur ^ 1][e][tid] = (tid > 0) ? buf[cur][e][tid - 1] : 0;
  for (int k = 0; k < TOKENS / 256; ++k) {
    const int t = t0 + k;
    const int e = eidx[t];
    const int p = buf[cur ^ 1][e][tid]++;
    if (p < CAPACITY) src[e * CAPACITY + p] = t;   // p>=CAP => token dropped
  }
}

// ---------------- dispatch: scatter tokens (f32 -> bf16) into [E*CAP, D]; zero empty slots
__global__ void dispatch_kernel(const float* __restrict__ tokens, const int* __restrict__ src,
                                __bf16* __restrict__ Xb) {
  const int slot = blockIdx.x;            // E*CAP blocks
  const int tid  = threadIdx.x;           // 256 threads, 4 elems each
  const int t = src[slot];
  bf16x4* dst = (bf16x4*)(Xb + (size_t)slot * DDIM);
  bf16x4 o;
  if (t >= 0) {
    const f32x4 v = ((const f32x4*)(tokens + (size_t)t * DDIM))[tid];
    o[0] = (__bf16)v[0]; o[1] = (__bf16)v[1]; o[2] = (__bf16)v[2]; o[3] = (__bf16)v[3];
  } else {
    o[0] = (__bf16)0.f; o[1] = (__bf16)0.f; o[2] = (__bf16)0.f; o[3] = (__bf16)0.f;
  }
  dst[tid] = o;
}

// ---------------- weight convert f32->bf16 with transpose: w[e][R][C] -> wt[e][C][R] ------
__global__ void transpose_convert_kernel(const float* __restrict__ w, __bf16* __restrict__ wt,
                                         int R, int C) {
  __shared__ __bf16 tile[64][66];         // pad 2: conflict-free transpose
  const int e = blockIdx.z;
  const float* wp = w + (size_t)e * R * C;
  __bf16* op = wt + (size_t)e * R * C;
  const int c0 = blockIdx.x * 64, r0 = blockIdx.y * 64;
  const int tid = threadIdx.x;            // 256 threads
#pragma unroll
  for (int p = 0; p < 4; ++p) {           // load 16 rows/pass, f32x4 per thread
    const int r = p * 16 + (tid >> 4);
    const int c = (tid & 15) * 4;
    const f32x4 v = *(const f32x4*)(wp + (size_t)(r0 + r) * C + c0 + c);
    tile[r][c]     = (__bf16)v[0]; tile[r][c + 1] = (__bf16)v[1];
    tile[r][c + 2] = (__bf16)v[2]; tile[r][c + 3] = (__bf16)v[3];
  }
  __syncthreads();
#pragma unroll
  for (int p = 0; p < 2; ++p) {           // store 32 out-rows/pass, bf16x8 per thread
    const int c  = p * 32 + (tid >> 3);
    const int rg = (tid & 7) * 8;
    bf16x8 o;
#pragma unroll
    for (int i = 0; i < 8; ++i) o[i] = tile[rg + i][c];
    *(bf16x8*)(op + (size_t)(c0 + c) * R + r0 + rg) = o;
  }
}

// ---------------- GEMM1: 256x256 tile, BK=64, 8 waves, m201-style 4-phase/K-tile ----------
// H[e] = relu(Xb[e][M,K] @ W1T[e][N,K]^T) -> bf16.  The verified 8-phase/2-tile template
// (m248v2: grouped K=1024 @256², 2ph=666 -> full 848 TF), expressed per-tile:
//   ph1: ds_read all kk0 frags  + stage (u+1).B0 -> bar -> MFMA mf0-3 x kk0
//   ph2: ds_read all kk1 frags  + stage (u+1).B1 -> bar -> MFMA mf4-7 x kk0
//   ph3:                          stage (u+2).A0 -> bar -> MFMA mf0-3 x kk1
//   ph4:                          stage (u+2).A1 + vmcnt(4) -> bar -> MFMA mf4-7 x kk1
// Overwrite-safety: each staged half's last reader phase is barrier-separated (A halves
// read only in ph1-2 of their tile; B halves likewise; t and t+2 share a buffer parity
// but t's reads finish at ph2 < ph3-4 staging). vmcnt ledger: outstanding <=12; the
// oldest 8 retired by vmcnt(4) are exactly tiles u+1's A (staged 1 tile ago) + B (ph1-2),
// so the next tile's ds_reads are safe; (u+2).A stays in flight across barriers (T4).
// LDS 128KB (1 block/CU, 8 waves); swizzle = proven 0-conflict scheme on [128][64] halves.
__global__ __launch_bounds__(512, 2)
void gemm1_kernel(const __bf16* __restrict__ A, const __bf16* __restrict__ B,
                  __bf16* __restrict__ Cbf, const int* __restrict__ counts,
                  int K, size_t sA, size_t sB, size_t sC) {
  constexpr int N  = FDIM;
  constexpr int NX = N / 256;             // 16
  __shared__ __bf16 lds[2][2][2][128 * 64];   // [buf][opA0B1][half][128r x 64k] = 128 KB

  const int nwg = NX * NYT1 * NEXP;       // 640
  int wg = blockIdx.x;
  wg = (wg & 7) * (nwg >> 3) + (wg >> 3); // bijective XCD swizzle (nwg % 8 == 0)
  const int e   = wg / (NX * NYT1);
  const int rem = wg - e * (NX * NYT1);
  const int ty  = rem % NYT1;             // y fastest: consecutive ids share B-panel (L2)
  const int tx  = rem / NYT1;
  const int m0  = ty * 256, n0 = tx * 256;

  const int cnt   = counts[e];            // M-tile skip (256-row granularity)
  const int tiles = (cnt + 255) >> 8;
  if (ty >= ((tiles < NYT1) ? tiles : NYT1)) return;

  const __bf16* Ae = A + (size_t)e * sA;
  const __bf16* Be = B + (size_t)e * sB;
  const int tid = threadIdx.x;
  const int wid = tid >> 6, lane = tid & 63;
  const int wm = wid >> 2, wn = wid & 3;  // 2M x 4N wave grid; per-wave out 128 x 64
  const int rl = lane & 15, gl = lane >> 4;

  f32x4 acc[8][4];
#pragma unroll
  for (int m = 0; m < 8; ++m)
#pragma unroll
    for (int n = 0; n < 4; ++n) acc[m][n] = (f32x4){0.f, 0.f, 0.f, 0.f};

  // stage one 128x64 half-tile (16KB): 2 async16/thread; LDS dest wave-uniform chunk,
  // per-lane XOR swizzle folded into the GLOBAL source (m173; 0 conflicts, proven)
  auto stageA = [&](int c, int half, int kt) {
    const __bf16* base = Ae + (size_t)(m0 + half * 128) * K + kt * 64;
#pragma unroll
    for (int i = 0; i < 2; ++i) {
      const int chunk = i * 8 + wid;      // 0..15, uniform per wave
      const int s = chunk * 64 + lane;    // 16B slot 0..1023
      const int row = s >> 3, cg = (s & 7) ^ (row & 7);
      async16(base + (size_t)row * K + cg * 8, (char*)&lds[c][0][half][0] + chunk * 1024);
    }
  };
  auto stageB = [&](int c, int half, int kt) {
    const __bf16* base = Be + (size_t)(n0 + half * 128) * K + kt * 64;
#pragma unroll
    for (int i = 0; i < 2; ++i) {
      const int chunk = i * 8 + wid;
      const int s = chunk * 64 + lane;
      const int row = s >> 3, cg = (s & 7) ^ (row & 7);
      async16(base + (size_t)row * K + cg * 8, (char*)&lds[c][1][half][0] + chunk * 1024);
    }
  };
  auto rdA = [&](int c, int mf, int kk) -> bf16x8 {
    const int row = mf * 16 + rl;         // within this wave's A-half (wm)
    const int g = (kk * 4 + gl) ^ (row & 7);
    return *(const bf16x8*)((const char*)&lds[c][0][wm][0] + row * 128 + g * 16);
  };
  auto rdB = [&](int c, int nf, int kk) -> bf16x8 {
    const int rb = wn * 64 + nf * 16 + rl;    // 0..255
    const int half = rb >> 7, row = rb & 127;
    const int g = (kk * 4 + gl) ^ (row & 7);
    return *(const bf16x8*)((const char*)&lds[c][1][half][0] + row * 128 + g * 16);
  };

  const int nkt = K >> 6;                 // 16
  // prologue: tile0 all 4 halves + tile1 A halves (12 issues); tile0 landed, t1.A in flight
  stageA(0, 0, 0); stageA(0, 1, 0); stageB(0, 0, 0); stageB(0, 1, 0);
  stageA(1, 0, 1); stageA(1, 1, 1);
  asm volatile("s_waitcnt vmcnt(4)" ::: "memory");
  SBAR;

  for (int u = 0; u < nkt; ++u) {
    const int c = u & 1;
    bf16x8 a0[8], a1[8], b0[4], b1[4];
    // ---- ph1 ----
#pragma unroll
    for (int mf = 0; mf < 8; ++mf) a0[mf] = rdA(c, mf, 0);
#pragma unroll
    for (int nf = 0; nf < 4; ++nf) b0[nf] = rdB(c, nf, 0);
    if (u + 1 < nkt) stageB(c ^ 1, 0, u + 1);
    SBAR;
    __builtin_amdgcn_s_setprio(1);
#pragma unroll
    for (int mf = 0; mf < 4; ++mf)
#pragma unroll
      for (int nf = 0; nf < 4; ++nf)
        acc[mf][nf] = __builtin_amdgcn_mfma_f32_16x16x32_bf16(a0[mf], b0[nf], acc[mf][nf], 0, 0, 0);
    __builtin_amdgcn_s_setprio(0);
    // ---- ph2 ----
#pragma unroll
    for (int mf = 0; mf < 8; ++mf) a1[mf] = rdA(c, mf, 1);
#pragma unroll
    for (int nf = 0; nf < 4; ++nf) b1[nf] = rdB(c, nf, 1);
    if (u + 1 < nkt) stageB(c ^ 1, 1, u + 1);
    SBAR;
    __builtin_amdgcn_s_setprio(1);
#pragma unroll
    for (int mf = 4; mf < 8; ++mf)
#pragma unroll
      for (int nf = 0; nf < 4; ++nf)
        acc[mf][nf] = __builtin_amdgcn_mfma_f32_16x16x32_bf16(a0[mf], b0[nf], acc[mf][nf], 0, 0, 0);
    __builtin_amdgcn_s_setprio(0);
    // ---- ph3 ----
    if (u + 2 < nkt) stageA(c, 0, u + 2);
    SBAR;
    __builtin_amdgcn_s_setprio(1);
#pragma unroll
    for (int mf = 0; mf < 4; ++mf)
#pragma unroll
      for (int nf = 0; nf < 4; ++nf)
        acc[mf][nf] = __builtin_amdgcn_mfma_f32_16x16x32_bf16(a1[mf], b1[nf], acc[mf][nf], 0, 0, 0);
    __builtin_amdgcn_s_setprio(0);
    // ---- ph4 ----
    if (u + 2 < nkt) {
      stageA(c, 1, u + 2);
      asm volatile("s_waitcnt vmcnt(4)" ::: "memory");  // (u+1) fully landed; (u+2).A in flight
    } else {
      asm volatile("s_waitcnt vmcnt(0)" ::: "memory");  // epilogue drain
    }
    SBAR;
    __builtin_amdgcn_s_setprio(1);
#pragma unroll
    for (int mf = 4; mf < 8; ++mf)
#pragma unroll
      for (int nf = 0; nf < 4; ++nf)
        acc[mf][nf] = __builtin_amdgcn_mfma_f32_16x16x32_bf16(a1[mf], b1[nf], acc[mf][nf], 0, 0, 0);
    __builtin_amdgcn_s_setprio(0);
  }

  // C/D layout: col = lane&15, row = (lane>>4)*4 + reg  [m89/m91 verified]
  __bf16* Ce = Cbf + (size_t)e * sC;
#pragma unroll
  for (int mf = 0; mf < 8; ++mf)
#pragma unroll
    for (int j = 0; j < 4; ++j) {
      const int row = m0 + wm * 128 + mf * 16 + gl * 4 + j;
#pragma unroll
      for (int nf = 0; nf < 4; ++nf) {
        const int col = n0 + wn * 64 + nf * 16 + rl;
        float v = acc[mf][nf][j];
        v = v > 0.f ? v : 0.f;            // fused ReLU
        Ce[(size_t)row * N + col] = (__bf16)v;
      }
    }
}

// ---------------- GEMM2: 128x128, BK=64, 4 waves, fused f32-W transpose (R8, 146us) -------
// Frozen at measured best while gemm1 tests the 8-phase template.
__global__ __launch_bounds__(256, 2)
void gemm2_kernel(const __bf16* __restrict__ A, const float* __restrict__ Bw,
                  float* __restrict__ out, const int* __restrict__ src,
                  const float* __restrict__ prob, const int* __restrict__ counts,
                  int K, size_t sA, size_t sBw) {
  constexpr int N  = DDIM;
  constexpr int NX = N / 128;
  __shared__ __bf16 lds[2][128 * 64];     // [0]=A tile [128 m][64 k], [1]=B tile [128 n][64 k]

  const int nwg = NX * NYT * NEXP;
  int wg = blockIdx.x;
  wg = (wg & 7) * (nwg >> 3) + (wg >> 3); // bijective XCD swizzle (nwg % 8 == 0)
  const int e   = wg / (NX * NYT);
  const int rem = wg - e * (NX * NYT);
  const int ty  = rem % NYT;
  const int tx  = rem / NYT;
  const int m0  = ty * 128, n0 = tx * 128;

  const int cnt   = counts[e];            // M-tile skip
  const int tiles = (cnt + 127) >> 7;
  if (ty >= ((tiles < NYT) ? tiles : NYT)) return;

  const __bf16* Ae = A + (size_t)e * sA;
  const float*  Be = Bw + (size_t)e * sBw;     // [K][N] f32
  const int tid = threadIdx.x;
  const int wid = tid >> 6, lane = tid & 63;
  const int wm = wid >> 1, wn = wid & 1;
  const int rl = lane & 15, gl = lane >> 4;
  const int nq = tid & 31;                // B staging: n-quad (cols 4nq..4nq+3)
  const int kb = tid >> 5;                // B staging: k-granule (rows 8kb..8kb+7)

  f32x4 acc[4][4];
#pragma unroll
  for (int m = 0; m < 4; ++m)
#pragma unroll
    for (int n = 0; n < 4; ++n) acc[m][n] = (f32x4){0.f, 0.f, 0.f, 0.f};

  for (int kt = 0; kt < K; kt += 64) {
    // B: coalesced f32 reads (rows k, consecutive n)
    f32x4 r[8];
#pragma unroll
    for (int i = 0; i < 8; ++i)
      r[i] = *(const f32x4*)(Be + (size_t)(kt + kb * 8 + i) * N + n0 + nq * 4);
    // A: async16, source pre-swizzled (m173 pattern)
#pragma unroll
    for (int i = 0; i < 4; ++i) {
      const int s   = (wid * 4 + i) * 64 + lane;
      const int row = s >> 3;
      const int cg  = (s & 7) ^ (row & 7);
      async16(Ae + (size_t)(m0 + row) * K + kt + cg * 8, &lds[0][(wid * 4 + i) * 512]);
    }
    // B: convert + transposed swizzled ds_write_b128
#pragma unroll
    for (int i2 = 0; i2 < 4; ++i2) {
      const int n  = nq * 4 + i2;
      const int sl = kb ^ (n & 7) ^ ((n >> 3) & 7);
      bf16x8 o;
#pragma unroll
      for (int i = 0; i < 8; ++i) o[i] = (__bf16)r[i][i2];
      *(bf16x8*)((char*)&lds[1][0] + n * 128 + sl * 16) = o;
    }
    __syncthreads();                      // drains vmcnt (async16) + lgkmcnt (ds_write)
    const char* la = (const char*)&lds[0][0];
    const char* lb = (const char*)&lds[1][0];
#pragma unroll
    for (int kk = 0; kk < 2; ++kk) {
      bf16x8 af[4], bv[4];
#pragma unroll
      for (int m = 0; m < 4; ++m) {
        const int rowin = wm * 64 + m * 16 + rl;
        af[m] = *(const bf16x8*)(la + rowin * 128 + (((kk * 4 + gl) ^ (rowin & 7)) * 16));
      }
#pragma unroll
      for (int n = 0; n < 4; ++n) {
        const int rowin = wn * 64 + n * 16 + rl;
        const int sl = (kk * 4 + gl) ^ (rowin & 7) ^ ((rowin >> 3) & 7);
        bv[n] = *(const bf16x8*)(lb + rowin * 128 + sl * 16);
      }
#pragma unroll
      for (int m = 0; m < 4; ++m)
#pragma unroll
        for (int n = 0; n < 4; ++n)
          acc[m][n] = __builtin_amdgcn_mfma_f32_16x16x32_bf16(af[m], bv[n], acc[m][n], 0, 0, 0);
    }
    __syncthreads();
  }

  // epilogue: fused combine (scale + scatter)
#pragma unroll
  for (int m = 0; m < 4; ++m)
#pragma unroll
    for (int j = 0; j < 4; ++j) {
      const int slot = m0 + wm * 64 + m * 16 + gl * 4 + j;
      const int t = src[e * CAPACITY + slot];
      if (t >= 0) {
        const float p = prob[t];
        float* op = out + (size_t)t * N;
#pragma unroll
        for (int n = 0; n < 4; ++n) {
          const int col = n0 + wn * 64 + n * 16 + rl;
          op[col] = p * acc[m][n][j];
        }
      }
    }
}

extern "C" void kernel_launch(void* const* d_in, const int* in_sizes, int n_in,
                              void* d_out, int out_size, void* d_ws, size_t ws_size,
                              hipStream_t stream) {
  const float* x  = (const float*)d_in[0];
  const float* gw = (const float*)d_in[1];
  const float* w1 = (const float*)d_in[2];
  const float* w2 = (const float*)d_in[3];
  float* out = (float*)d_out;

  char* ws = (char*)d_ws;
  size_t off = 0;
  auto alloc = [&](size_t bytes) {
    void* p = ws + off;
    off += (bytes + 255) & ~(size_t)255;
    return p;
  };
  __bf16* W1bT = (__bf16*)alloc((size_t)NEXP * FDIM * DDIM * 2);   // [E][F][D] bf16
  __bf16* Xb   = (__bf16*)alloc((size_t)NEXP * CAPACITY * DDIM * 2);
  __bf16* Hb   = (__bf16*)alloc((size_t)NEXP * CAPACITY * FDIM * 2);
  int*   eidx  = (int*)alloc(TOKENS * sizeof(int));
  float* prob  = (float*)alloc(TOKENS * sizeof(float));
  int*   srcm  = (int*)alloc(NEXP * CAPACITY * sizeof(int));
  int*   cnts  = (int*)alloc(NEXP * sizeof(int));
  (void)ws_size; (void)in_sizes; (void)n_in;

  hipMemsetAsync(d_out, 0, (size_t)out_size * sizeof(float), stream);  // dropped tokens -> 0

  gate_kernel<<<TOKENS, 64, 0, stream>>>(x, gw, eidx, prob);
  scan_kernel<<<1, 256, 0, stream>>>(eidx, srcm, cnts);
  dispatch_kernel<<<NEXP * CAPACITY, 256, 0, stream>>>(x, srcm, Xb);
  transpose_convert_kernel<<<dim3(FDIM / 64, DDIM / 64, NEXP), 256, 0, stream>>>(
      w1, W1bT, DDIM, FDIM);
  // H = relu(Xb @ W1^T): 256² 8-wave 4-phase template, grid = 16*5*8 = 640
  gemm1_kernel<<<(FDIM / 256) * NYT1 * NEXP, 512, 0, stream>>>(
      Xb, W1bT, Hb, cnts,
      DDIM, (size_t)CAPACITY * DDIM, (size_t)FDIM * DDIM, (size_t)CAPACITY * FDIM);
  // out[t] = prob[t] * (H @ W2)[slot]: f32 W2 direct, BK=64, grid = 8*10*8 = 640
  gemm2_kernel<<<(DDIM / 128) * NYT * NEXP, 256, 0, stream>>>(
      Hb, w2, out, srcm, prob, cnts,
      FDIM, (size_t)CAPACITY * FDIM, (size_t)FDIM * DDIM);
}